// Round 5
// baseline (534.433 us; speedup 1.0000x reference)
//
#include <hip/hip_runtime.h>
#include <math.h>

// Problem constants (match setup_inputs)
#define BATCH 8
#define T_LEN 25000
#define NW    1000
#define WS    25
#define D0    256
#define H     128

typedef __bf16 bf16;
typedef bf16 bf16x8 __attribute__((ext_vector_type(8)));
typedef bf16 bf16x4 __attribute__((ext_vector_type(4)));
typedef float f32x4 __attribute__((ext_vector_type(4)));
typedef float f32x16 __attribute__((ext_vector_type(16)));

// tanh-form GELU via v_exp_f32. |err| <= ~3e-3 absolute.
__device__ __forceinline__ float gelu_fast(float x) {
    float y = 0.7978845608f * x * (1.0f + 0.044715f * x * x);
    float e = __expf(2.0f * y);
    float t = 1.0f - 2.0f * __builtin_amdgcn_rcpf(e + 1.0f);
    return 0.5f * x * (1.0f + t);
}

// ---------------------------------------------------------------------------
// Weight repack for 32x32x16 A-fragments:
//   dst[ ((k*KSn + ks)*4 + mt)*512 + lane*8 + j ]
//     = w[ co = mt*32 + (lane&31) ][ ci = ks*16 + (lane>>5)*8 + j ][ k ]
// ---------------------------------------------------------------------------
__device__ __forceinline__ void repack_one(const float* __restrict__ w,
                                           bf16* __restrict__ dst, int idx,
                                           int Cin, int K, int KSn) {
    int j    = idx & 7;
    int lane = (idx >> 3) & 63;
    int mt   = (idx >> 9) & 3;
    int u    = idx >> 11;
    int ks   = u % KSn;
    int k    = u / KSn;
    int co = mt * 32 + (lane & 31);
    int ci = ks * 16 + (lane >> 5) * 8 + j;
    dst[idx] = (bf16)w[(co * Cin + ci) * K + k];
}

__global__ void prep_kernel(const float* __restrict__ c0w, const float* __restrict__ c1w,
                            const float* __restrict__ c2w, const float* __restrict__ hw1,
                            bf16* __restrict__ p0, bf16* __restrict__ p1,
                            bf16* __restrict__ p2, bf16* __restrict__ hw1b) {
    int t = blockIdx.x * 256 + threadIdx.x;
    if (t < 229376) {
        repack_one(c0w, p0, t, 256, 7, 16);
    } else if (t < 311296) {
        repack_one(c1w, p1, t - 229376, 128, 5, 8);
    } else if (t < 393216) {
        repack_one(c2w, p2, t - 311296, 128, 5, 8);
    } else if (t < 409600) {
        int i = t - 393216;
        hw1b[i] = (bf16)hw1[i];
    }
}

// ---------------------------------------------------------------------------
// Fused critic, W=2 windows/block, 32x32x16 MFMA. 256 thr = 4 waves; each wave
// owns one 32-row co tile (m-tile = wv) and both windows (2 n-tiles of 32).
//
// LDS (36864 B -> 4 blocks/CU by LDS):
//  xT  bf16[62][264] @0      rows 0..30 win A (l+3), 31..61 win B (l+9); 32736 B
//  a1T bf16[58][136] @0      OVERLAYS xT (dead after conv0); rows: win A l+2,
//                            win B l+2+29
//  a2T bf16[58][136] @16384  also inside old xT region
//  feat float[256]   @34816
//  hbuf float[256]   @35840
// Garbage-column over-reads (discarded l>=25): conv0 <= row 68 of xT (36432 B),
// conv1 <= byte 17680, conv2 <= byte 34064 — all in-bounds, all read-only
// w.r.t. concurrently-written *valid* data. Valid-column reads never cross
// regions (conv1 valid <= 15776 < 16384; conv2 valid <= 32160 < 34816).
//
// __launch_bounds__(256,3): R4's (256,4) capped regs at 128 and spilled the
// f32x16 accumulators to scratch (WRITE_SIZE 176 MB, FETCH +86 MB, L3 blown).
// (256,3) gives ~170 regs — R3 showed zero spill at this cap.
// ---------------------------------------------------------------------------
#define XT_LD 264
#define A_LD  136
#define OFF_A2   16384
#define OFF_FEAT 34816
#define OFF_H    35840
#define SMEM_BYTES 36864

__global__ __launch_bounds__(256, 3)
void critic_kernel(const float* __restrict__ lat,
                   const bf16* __restrict__ p0, const float* __restrict__ b0,
                   const bf16* __restrict__ p1, const float* __restrict__ b1,
                   const bf16* __restrict__ p2, const float* __restrict__ b2,
                   const bf16* __restrict__ hw1b, const float* __restrict__ hb1,
                   const float* __restrict__ hw2, const float* __restrict__ hb2,
                   float* __restrict__ scores_tmp) {
    __shared__ __align__(16) char smem[SMEM_BYTES];
    bf16  (*xT)[XT_LD]  = (bf16(*)[XT_LD])smem;
    bf16  (*a1T)[A_LD]  = (bf16(*)[A_LD])smem;            // overlays xT after conv0
    bf16  (*a2T)[A_LD]  = (bf16(*)[A_LD])(smem + OFF_A2); // ditto
    float* feat = (float*)(smem + OFF_FEAT);
    float* hbuf = (float*)(smem + OFF_H);

    const int tid = threadIdx.x;
    const int bx  = blockIdx.x;
    const int b   = bx / (NW / 2);
    const int wi  = bx % (NW / 2);
    const int w0  = 2 * wi;

    // ---- stage 2 adjacent windows: 50*256 floats = 3200 float4 ----
    {
        const float4* src4 = (const float4*)(lat + ((size_t)b * T_LEN + (size_t)w0 * WS) * D0);
        #pragma unroll
        for (int it = 0; it < 12; ++it) {
            int g = tid + it * 256;
            int l = g >> 6, c0 = (g & 63) * 4;
            int r = (l < 25) ? (l + 3) : (l + 9);
            float4 v = src4[g];
            bf16x4 o = {(bf16)v.x, (bf16)v.y, (bf16)v.z, (bf16)v.w};
            *(bf16x4*)&xT[r][c0] = o;
        }
        if (tid < 128) {
            int g = 3072 + tid;
            int l = g >> 6, c0 = (g & 63) * 4;
            int r = (l < 25) ? (l + 3) : (l + 9);
            float4 v = src4[g];
            bf16x4 o = {(bf16)v.x, (bf16)v.y, (bf16)v.z, (bf16)v.w};
            *(bf16x4*)&xT[r][c0] = o;
        }
        // zero xT pad rows {0,1,2,28,29,30} + {31,32,33,59,60,61}: 768 bf16x4
        bf16x4 z4 = {};
        #pragma unroll
        for (int it = 0; it < 3; ++it) {
            int i = tid + it * 256;
            if (i < 768) {
                int rr = i >> 6;
                int r = (rr < 3) ? rr : ((rr < 9) ? rr + 25 : rr + 50);
                *(bf16x4*)&xT[r][(i & 63) * 4] = z4;
            }
        }
    }
    __syncthreads();

    const int lane = tid & 63, wv = tid >> 6;
    const int n5 = lane & 31, q2 = lane >> 5;
    const bf16* xb = &xT[n5][q2 * 8];        // + row*XT_LD + ks*16

    // ================= conv0: Cin=256 (16 K-steps), K=7, pad=3 =================
    f32x16 accA = {}, accB = {};
    {
        const bf16x8* A = (const bf16x8*)p0 + (size_t)wv * 64 + lane;
        #pragma unroll
        for (int k = 0; k < 7; ++k) {
            #pragma unroll
            for (int ks = 0; ks < 16; ++ks) {
                bf16x8 a = A[(k * 16 + ks) * 256];
                bf16x8 bbA = *(const bf16x8*)(xb + k * XT_LD + ks * 16);
                bf16x8 bbB = *(const bf16x8*)(xb + (k + 31) * XT_LD + ks * 16);
                accA = __builtin_amdgcn_mfma_f32_32x32x16_bf16(a, bbA, accA, 0, 0, 0);
                accB = __builtin_amdgcn_mfma_f32_32x32x16_bf16(a, bbB, accB, 0, 0, 0);
            }
        }
    }
    __syncthreads();   // xT dead; region reused for a1T/a2T
    // zero a1T+a2T pad rows {0,1,27,28,29,30,56,57} each: 512 bf16x4
    {
        bf16x4 z4 = {};
        #pragma unroll
        for (int it = 0; it < 2; ++it) {
            int i = tid + it * 256;
            int rr = (i >> 5) & 7;
            int r = (rr < 2) ? rr : ((rr < 6) ? rr + 25 : rr + 50);
            int c0 = (i & 31) * 4;
            if (i < 256) *(bf16x4*)&a1T[r][c0] = z4;
            else         *(bf16x4*)&a2T[r][c0] = z4;
        }
    }
    // conv0 epilogue: gelu -> a1T  (C/D: col=n5, row = (reg&3)+8*(reg>>2)+4*q2)
    #pragma unroll
    for (int rq = 0; rq < 4; ++rq) {
        int co0 = wv * 32 + 8 * rq + 4 * q2;
        f32x4 bv = *(const f32x4*)&b0[co0];
        if (n5 < 25) {
            bf16x4 vA, vB;
            #pragma unroll
            for (int r = 0; r < 4; ++r) {
                vA[r] = (bf16)gelu_fast(accA[4 * rq + r] + bv[r]);
                vB[r] = (bf16)gelu_fast(accB[4 * rq + r] + bv[r]);
            }
            *(bf16x4*)&a1T[n5 + 2][co0] = vA;
            *(bf16x4*)&a1T[n5 + 2 + 29][co0] = vB;
        }
    }
    __syncthreads();

    // ================= conv1: Cin=128 (8 K-steps), K=5, pad=2 =================
    f32x16 c1A = {}, c1B = {};
    {
        const bf16* ab = &a1T[n5][q2 * 8];
        const bf16x8* A = (const bf16x8*)p1 + (size_t)wv * 64 + lane;
        #pragma unroll
        for (int k = 0; k < 5; ++k) {
            #pragma unroll
            for (int ks = 0; ks < 8; ++ks) {
                bf16x8 a = A[(k * 8 + ks) * 256];
                bf16x8 bbA = *(const bf16x8*)(ab + k * A_LD + ks * 16);
                bf16x8 bbB = *(const bf16x8*)(ab + (k + 29) * A_LD + ks * 16);
                c1A = __builtin_amdgcn_mfma_f32_32x32x16_bf16(a, bbA, c1A, 0, 0, 0);
                c1B = __builtin_amdgcn_mfma_f32_32x32x16_bf16(a, bbB, c1B, 0, 0, 0);
            }
        }
    }
    // epilogue -> a2T (valid conv1 reads never touch a2T region; garbage-col
    // overlap is discarded)
    #pragma unroll
    for (int rq = 0; rq < 4; ++rq) {
        int co0 = wv * 32 + 8 * rq + 4 * q2;
        f32x4 bv = *(const f32x4*)&b1[co0];
        if (n5 < 25) {
            bf16x4 vA, vB;
            #pragma unroll
            for (int r = 0; r < 4; ++r) {
                vA[r] = (bf16)gelu_fast(c1A[4 * rq + r] + bv[r]);
                vB[r] = (bf16)gelu_fast(c1B[4 * rq + r] + bv[r]);
            }
            *(bf16x4*)&a2T[n5 + 2][co0] = vA;
            *(bf16x4*)&a2T[n5 + 2 + 29][co0] = vB;
        }
    }
    __syncthreads();

    // ================= conv2: Cin=128 (8 K-steps), K=5, pad=2 =================
    f32x16 c2A = {}, c2B = {};
    {
        const bf16* ab = &a2T[n5][q2 * 8];
        const bf16x8* A = (const bf16x8*)p2 + (size_t)wv * 64 + lane;
        #pragma unroll
        for (int k = 0; k < 5; ++k) {
            #pragma unroll
            for (int ks = 0; ks < 8; ++ks) {
                bf16x8 a = A[(k * 8 + ks) * 256];
                bf16x8 bbA = *(const bf16x8*)(ab + k * A_LD + ks * 16);
                bf16x8 bbB = *(const bf16x8*)(ab + (k + 29) * A_LD + ks * 16);
                c2A = __builtin_amdgcn_mfma_f32_32x32x16_bf16(a, bbA, c2A, 0, 0, 0);
                c2B = __builtin_amdgcn_mfma_f32_32x32x16_bf16(a, bbB, c2B, 0, 0, 0);
            }
        }
    }
    // ===== register pooling: gelu + shuffle-reduce over l = n5 (bits 0..4) =====
    #pragma unroll
    for (int rq = 0; rq < 4; ++rq) {
        int co0 = wv * 32 + 8 * rq + 4 * q2;
        f32x4 bv = *(const f32x4*)&b2[co0];
        f32x4 poolA, poolB;
        #pragma unroll
        for (int r = 0; r < 4; ++r) {
            float sA = (n5 < 25) ? gelu_fast(c2A[4 * rq + r] + bv[r]) : 0.0f;
            float sB = (n5 < 25) ? gelu_fast(c2B[4 * rq + r] + bv[r]) : 0.0f;
            #pragma unroll
            for (int off = 1; off < 32; off <<= 1) {
                sA += __shfl_xor(sA, off);
                sB += __shfl_xor(sB, off);
            }
            poolA[r] = sA * 0.04f;
            poolB[r] = sB * 0.04f;
        }
        if (n5 == 0) {
            *(f32x4*)&feat[co0] = poolA;
            *(f32x4*)&feat[128 + co0] = poolB;
        }
    }
    __syncthreads();

    // ================= head (both windows, all 256 threads) =================
    {
        int win = tid >> 7, co = tid & 127;
        const bf16x8* row = (const bf16x8*)(hw1b + co * H);
        const float* f = feat + win * 128;
        float a = hb1[co];
        #pragma unroll
        for (int jv = 0; jv < 16; ++jv) {
            bf16x8 w8 = row[jv];
            #pragma unroll
            for (int u = 0; u < 8; ++u)
                a += (float)w8[u] * f[jv * 8 + u];
        }
        hbuf[tid] = gelu_fast(a);
    }
    __syncthreads();

    if (tid < 128) {
        int win = tid >> 6, j = tid & 63;
        const float* hb = hbuf + win * 128;
        float p = hw2[j] * hb[j] + hw2[j + 64] * hb[j + 64];
        #pragma unroll
        for (int off = 32; off > 0; off >>= 1) p += __shfl_down(p, off);
        if (j == 0) {
            float z = p + hb2[0];
            scores_tmp[b * NW + w0 + win] = 5.0f / (1.0f + expf(-z));
        }
    }
}

// ---------------------------------------------------------------------------
__global__ void finalize_kernel(const float* __restrict__ tmp, float* __restrict__ out) {
    int w = blockIdx.x * 256 + threadIdx.x;
    if (w < NW) {
        float s = 0.0f;
        #pragma unroll
        for (int b = 0; b < BATCH; ++b) s += tmp[b * NW + w];
        s *= 0.125f;
        out[w] = s;
        out[NW + w] = (s < 3.5f) ? 1.0f : 0.0f;
    }
}

// ---------------------------------------------------------------------------
extern "C" void kernel_launch(void* const* d_in, const int* in_sizes, int n_in,
                              void* d_out, int out_size, void* d_ws, size_t ws_size,
                              hipStream_t stream) {
    const float* lat  = (const float*)d_in[0];
    const float* c0w  = (const float*)d_in[1];
    const float* c0b  = (const float*)d_in[2];
    const float* c1w  = (const float*)d_in[3];
    const float* c1b  = (const float*)d_in[4];
    const float* c2w  = (const float*)d_in[5];
    const float* c2b  = (const float*)d_in[6];
    const float* hw1  = (const float*)d_in[7];
    const float* hb1  = (const float*)d_in[8];
    const float* hw2  = (const float*)d_in[9];
    const float* hb2  = (const float*)d_in[10];

    // workspace layout
    bf16* p0   = (bf16*)d_ws;                                 // 458752 B
    bf16* p1   = (bf16*)((char*)d_ws + 458752);               // 163840 B
    bf16* p2   = (bf16*)((char*)d_ws + 622592);               // 163840 B
    bf16* hw1b = (bf16*)((char*)d_ws + 786432);               //  32768 B
    float* tmp = (float*)((char*)d_ws + 819200);              //  32000 B

    prep_kernel<<<1600, 256, 0, stream>>>(c0w, c1w, c2w, hw1, p0, p1, p2, hw1b);
    critic_kernel<<<BATCH * (NW / 2), 256, 0, stream>>>(lat, p0, c0b, p1, c1b, p2, c2b,
                                                        hw1b, hb1, hw2, hb2, tmp);
    finalize_kernel<<<4, 256, 0, stream>>>(tmp, (float*)d_out);
}

// Round 6
// 464.878 us; speedup vs baseline: 1.1496x; 1.1496x over previous
//
#include <hip/hip_runtime.h>
#include <math.h>

// Problem constants (match setup_inputs)
#define BATCH 8
#define T_LEN 25000
#define NW    1000
#define WS    25
#define D0    256
#define H     128

typedef __bf16 bf16;
typedef bf16 bf16x8 __attribute__((ext_vector_type(8)));
typedef bf16 bf16x4 __attribute__((ext_vector_type(4)));
typedef float f32x4 __attribute__((ext_vector_type(4)));

// tanh-form GELU via v_exp_f32. |err| <= ~3e-3 absolute.
__device__ __forceinline__ float gelu_fast(float x) {
    float y = 0.7978845608f * x * (1.0f + 0.044715f * x * x);
    float e = __expf(2.0f * y);
    float t = 1.0f - 2.0f * __builtin_amdgcn_rcpf(e + 1.0f);
    return 0.5f * x * (1.0f + t);
}

// ---------------------------------------------------------------------------
// Weight repack (16x16x32 A-fragments, R3-verified):
//   dst[ ((k*KSn + ks)*8 + mt)*512 + lane*8 + j ]
//     = w[ co=mt*16+(lane&15) ][ ci=ks*32+(lane>>4)*8+j ][ k ]
// ---------------------------------------------------------------------------
__device__ __forceinline__ void repack_one(const float* __restrict__ w,
                                           bf16* __restrict__ dst, int idx,
                                           int Cin, int K, int KSn) {
    int j    = idx & 7;
    int lane = (idx >> 3) & 63;
    int mt   = (idx >> 9) & 7;
    int ks   = (idx >> 12) % KSn;
    int k    = idx / (4096 * KSn);
    int co = mt * 16 + (lane & 15);
    int ci = ks * 32 + (lane >> 4) * 8 + j;
    dst[idx] = (bf16)w[(co * Cin + ci) * K + k];
}

__global__ void prep_kernel(const float* __restrict__ c0w, const float* __restrict__ c1w,
                            const float* __restrict__ c2w, const float* __restrict__ hw1,
                            bf16* __restrict__ p0, bf16* __restrict__ p1,
                            bf16* __restrict__ p2, bf16* __restrict__ hw1b) {
    int t = blockIdx.x * 256 + threadIdx.x;
    if (t < 229376) {
        repack_one(c0w, p0, t, 256, 7, 8);
    } else if (t < 311296) {
        repack_one(c1w, p1, t - 229376, 128, 5, 4);
    } else if (t < 393216) {
        repack_one(c2w, p2, t - 311296, 128, 5, 4);
    } else if (t < 409600) {
        int i = t - 393216;
        hw1b[i] = (bf16)hw1[i];
    }
}

// ---------------------------------------------------------------------------
// Fused critic, W=4 windows/block, 16x16x32 MFMA (R3-verified layouts).
// 256 thr = 4 waves; each wave: 2 co m-tiles x 8 n-tiles (4 win x 2).
// Each A-fragment load now feeds 8 MFMAs (was 4 at W=2) -> 2x L2-latency
// coverage; per-window weight traffic halved.
//
// LDS (74848 B -> 2 blocks/CU):
//  xT  bf16[134][264] @0     win j rows 31j..31j+30 (l+3), tail rows 124..133
//                            garbage-only (fed to discarded cols). 70752 B
//  a1T bf16[123][136] @0     OVERLAY (xT dead after conv0); win j row = l+2+29j
//  a2T bf16[123][136] @33456 also inside xT region (33456+33456 <= 70752)
//  feat float[512]    @70752 (128 per window)
//  hbuf float[512]    @72800
// Bounds audit (byte offsets, incl. garbage-column over-reads):
//  conv0 reads  <= 130*528+480    = 69120 < 70752  OK
//  conv1 reads  <= 122*272+240    = 33424 < 33456 (a1T size) OK
//  conv2 reads  <= 33456+33424    = 66880 < 70752  OK
//  valid epilogue writes: a1T/a2T rows <= 113 -> disjoint from feat/hbuf.
// __launch_bounds__(256,2): 256-reg budget (R4 lesson: (256,4) spilled accs).
// ---------------------------------------------------------------------------
#define XT_LD 264
#define A_LD  136
#define OFF_A2   33456
#define OFF_FEAT 70752
#define OFF_H    72800
#define SMEM_BYTES 74848

__global__ __launch_bounds__(256, 2)
void critic_kernel(const float* __restrict__ lat,
                   const bf16* __restrict__ p0, const float* __restrict__ b0,
                   const bf16* __restrict__ p1, const float* __restrict__ b1,
                   const bf16* __restrict__ p2, const float* __restrict__ b2,
                   const bf16* __restrict__ hw1b, const float* __restrict__ hb1,
                   const float* __restrict__ hw2, const float* __restrict__ hb2,
                   float* __restrict__ scores_tmp) {
    __shared__ __align__(16) char smem[SMEM_BYTES];
    bf16  (*xT)[XT_LD]  = (bf16(*)[XT_LD])smem;
    bf16  (*a1T)[A_LD]  = (bf16(*)[A_LD])smem;            // overlays xT after conv0
    bf16  (*a2T)[A_LD]  = (bf16(*)[A_LD])(smem + OFF_A2); // ditto
    float* feat = (float*)(smem + OFF_FEAT);
    float* hbuf = (float*)(smem + OFF_H);

    const int tid = threadIdx.x;
    const int bx  = blockIdx.x;
    const int b   = bx / (NW / 4);
    const int wi  = bx % (NW / 4);
    const int w0  = 4 * wi;

    // ---- stage 4 adjacent windows: 100*256 floats = 6400 float4 ----
    {
        const float4* src4 = (const float4*)(lat + ((size_t)b * T_LEN + (size_t)w0 * WS) * D0);
        #pragma unroll
        for (int it = 0; it < 25; ++it) {
            int g = tid + it * 256;
            int l = g >> 6, c0 = (g & 63) * 4;
            int win = l / 25, lr = l - win * 25;
            int r = 31 * win + lr + 3;
            float4 v = src4[g];
            bf16x4 o = {(bf16)v.x, (bf16)v.y, (bf16)v.z, (bf16)v.w};
            *(bf16x4*)&xT[r][c0] = o;
        }
        // zero xT pad rows 31j+{0,1,2,28,29,30}, j=0..3: 24 rows x 64 bf16x4
        bf16x4 z4 = {};
        #pragma unroll
        for (int it = 0; it < 6; ++it) {
            int i = tid + it * 256;
            int rr = i >> 6, c0 = (i & 63) * 4;
            int j = rr / 6, t6 = rr - 6 * j;
            int r = 31 * j + ((t6 < 3) ? t6 : t6 + 25);
            *(bf16x4*)&xT[r][c0] = z4;
        }
    }
    __syncthreads();

    const int lane = tid & 63, wv = tid >> 6;
    const int m = lane & 15, q = lane >> 4;
    const bf16* xb  = &xT[m][q * 8];
    const bf16* a1b = &a1T[m][q * 8];

    // ================= conv0: Cin=256 (8 K-steps), K=7, pad=3 =================
    f32x4 acc[2][8] = {};
    {
        const bf16x8* A = (const bf16x8*)p0 + (size_t)wv * 64 + lane;
        #pragma unroll
        for (int k = 0; k < 7; ++k) {
            #pragma unroll
            for (int ks = 0; ks < 8; ++ks) {
                bf16x8 a0 = A[(k * 8 + ks) * 512];
                bf16x8 a1 = A[(k * 8 + ks) * 512 + 256];
                #pragma unroll
                for (int win = 0; win < 4; ++win) {
                    const bf16* pB = xb + (k + 31 * win) * XT_LD + ks * 32;
                    bf16x8 bb0 = *(const bf16x8*)(pB);
                    bf16x8 bb1 = *(const bf16x8*)(pB + 16 * XT_LD);
                    acc[0][2 * win]     = __builtin_amdgcn_mfma_f32_16x16x32_bf16(a0, bb0, acc[0][2 * win], 0, 0, 0);
                    acc[0][2 * win + 1] = __builtin_amdgcn_mfma_f32_16x16x32_bf16(a0, bb1, acc[0][2 * win + 1], 0, 0, 0);
                    acc[1][2 * win]     = __builtin_amdgcn_mfma_f32_16x16x32_bf16(a1, bb0, acc[1][2 * win], 0, 0, 0);
                    acc[1][2 * win + 1] = __builtin_amdgcn_mfma_f32_16x16x32_bf16(a1, bb1, acc[1][2 * win + 1], 0, 0, 0);
                }
            }
        }
    }
    __syncthreads();   // xT dead; region reused for a1T/a2T
    // zero a1T+a2T pad rows 29j+{0,1,27,28}: 16 rows x 32 bf16x4 each
    {
        bf16x4 z4 = {};
        #pragma unroll
        for (int it = 0; it < 4; ++it) {
            int i = tid + it * 256;
            int arr = i >> 9, rr = (i >> 5) & 15, c0 = (i & 31) * 4;
            int j = rr >> 2, t4 = rr & 3;
            int r = 29 * j + ((t4 < 2) ? t4 : t4 + 25);
            if (arr == 0) *(bf16x4*)&a1T[r][c0] = z4;
            else          *(bf16x4*)&a2T[r][c0] = z4;
        }
    }
    // conv0 epilogue: gelu -> a1T  (C/D: col=nt*16+m, row=q*4+r within tile)
    #pragma unroll
    for (int mt = 0; mt < 2; ++mt) {
        int co0 = (wv + 4 * mt) * 16 + q * 4;
        f32x4 bv = *(const f32x4*)&b0[co0];
        #pragma unroll
        for (int win = 0; win < 4; ++win) {
            #pragma unroll
            for (int nt = 0; nt < 2; ++nt) {
                int l = nt * 16 + m;
                if (l < 25) {
                    bf16x4 v;
                    #pragma unroll
                    for (int r = 0; r < 4; ++r)
                        v[r] = (bf16)gelu_fast(acc[mt][2 * win + nt][r] + bv[r]);
                    *(bf16x4*)&a1T[l + 2 + 29 * win][co0] = v;
                }
            }
        }
    }
    __syncthreads();

    // ================= conv1: Cin=128 (4 K-steps), K=5, pad=2 =================
    f32x4 c1[2][8] = {};
    {
        const bf16x8* A = (const bf16x8*)p1 + (size_t)wv * 64 + lane;
        #pragma unroll
        for (int k = 0; k < 5; ++k) {
            #pragma unroll
            for (int ks = 0; ks < 4; ++ks) {
                bf16x8 a0 = A[(k * 4 + ks) * 512];
                bf16x8 a1 = A[(k * 4 + ks) * 512 + 256];
                #pragma unroll
                for (int win = 0; win < 4; ++win) {
                    const bf16* pB = a1b + (k + 29 * win) * A_LD + ks * 32;
                    bf16x8 bb0 = *(const bf16x8*)(pB);
                    bf16x8 bb1 = *(const bf16x8*)(pB + 16 * A_LD);
                    c1[0][2 * win]     = __builtin_amdgcn_mfma_f32_16x16x32_bf16(a0, bb0, c1[0][2 * win], 0, 0, 0);
                    c1[0][2 * win + 1] = __builtin_amdgcn_mfma_f32_16x16x32_bf16(a0, bb1, c1[0][2 * win + 1], 0, 0, 0);
                    c1[1][2 * win]     = __builtin_amdgcn_mfma_f32_16x16x32_bf16(a1, bb0, c1[1][2 * win], 0, 0, 0);
                    c1[1][2 * win + 1] = __builtin_amdgcn_mfma_f32_16x16x32_bf16(a1, bb1, c1[1][2 * win + 1], 0, 0, 0);
                }
            }
        }
    }
    // epilogue -> a2T (valid conv1 reads stay below a2T; garbage discarded)
    #pragma unroll
    for (int mt = 0; mt < 2; ++mt) {
        int co0 = (wv + 4 * mt) * 16 + q * 4;
        f32x4 bv = *(const f32x4*)&b1[co0];
        #pragma unroll
        for (int win = 0; win < 4; ++win) {
            #pragma unroll
            for (int nt = 0; nt < 2; ++nt) {
                int l = nt * 16 + m;
                if (l < 25) {
                    bf16x4 v;
                    #pragma unroll
                    for (int r = 0; r < 4; ++r)
                        v[r] = (bf16)gelu_fast(c1[mt][2 * win + nt][r] + bv[r]);
                    *(bf16x4*)&a2T[l + 2 + 29 * win][co0] = v;
                }
            }
        }
    }
    __syncthreads();

    // ================= conv2: Cin=128 (4 K-steps), K=5, pad=2 =================
    f32x4 c2[2][8] = {};
    {
        const bf16* a2b = &a2T[m][q * 8];
        const bf16x8* A = (const bf16x8*)p2 + (size_t)wv * 64 + lane;
        #pragma unroll
        for (int k = 0; k < 5; ++k) {
            #pragma unroll
            for (int ks = 0; ks < 4; ++ks) {
                bf16x8 a0 = A[(k * 4 + ks) * 512];
                bf16x8 a1 = A[(k * 4 + ks) * 512 + 256];
                #pragma unroll
                for (int win = 0; win < 4; ++win) {
                    const bf16* pB = a2b + (k + 29 * win) * A_LD + ks * 32;
                    bf16x8 bb0 = *(const bf16x8*)(pB);
                    bf16x8 bb1 = *(const bf16x8*)(pB + 16 * A_LD);
                    c2[0][2 * win]     = __builtin_amdgcn_mfma_f32_16x16x32_bf16(a0, bb0, c2[0][2 * win], 0, 0, 0);
                    c2[0][2 * win + 1] = __builtin_amdgcn_mfma_f32_16x16x32_bf16(a0, bb1, c2[0][2 * win + 1], 0, 0, 0);
                    c2[1][2 * win]     = __builtin_amdgcn_mfma_f32_16x16x32_bf16(a1, bb0, c2[1][2 * win], 0, 0, 0);
                    c2[1][2 * win + 1] = __builtin_amdgcn_mfma_f32_16x16x32_bf16(a1, bb1, c2[1][2 * win + 1], 0, 0, 0);
                }
            }
        }
    }
    // ===== register pooling: gelu + shuffle-reduce over l (lane bits 0-3) =====
    #pragma unroll
    for (int mt = 0; mt < 2; ++mt) {
        int co0 = (wv + 4 * mt) * 16 + q * 4;
        f32x4 bv = *(const f32x4*)&b2[co0];
        #pragma unroll
        for (int win = 0; win < 4; ++win) {
            f32x4 pool;
            #pragma unroll
            for (int r = 0; r < 4; ++r) {
                float s  = gelu_fast(c2[mt][2 * win][r] + bv[r]);       // l = m < 25
                float g1 = gelu_fast(c2[mt][2 * win + 1][r] + bv[r]);   // l = 16+m
                s += (m < 9) ? g1 : 0.0f;
                s += __shfl_xor(s, 1);
                s += __shfl_xor(s, 2);
                s += __shfl_xor(s, 4);
                s += __shfl_xor(s, 8);
                pool[r] = s * 0.04f;
            }
            if (m == 0) *(f32x4*)&feat[win * 128 + co0] = pool;
        }
    }
    __syncthreads();

    // ===== head: 512 dots of length 128; each thread does wins {wb, wb+2} =====
    {
        int wb = tid >> 7, co = tid & 127;
        const bf16x8* row = (const bf16x8*)(hw1b + co * H);
        const float* f0 = feat + wb * 128;
        const float* f1 = feat + (wb + 2) * 128;
        float a0h = hb1[co], a1h = a0h;
        #pragma unroll
        for (int jv = 0; jv < 16; ++jv) {
            bf16x8 w8 = row[jv];
            #pragma unroll
            for (int u = 0; u < 8; ++u) {
                float wf = (float)w8[u];
                a0h += wf * f0[jv * 8 + u];
                a1h += wf * f1[jv * 8 + u];
            }
        }
        hbuf[wb * 128 + co] = gelu_fast(a0h);
        hbuf[(wb + 2) * 128 + co] = gelu_fast(a1h);
    }
    __syncthreads();

    {
        int win = tid >> 6, j = tid & 63;     // 4 waves -> 4 windows
        const float* hb = hbuf + win * 128;
        float p = hw2[j] * hb[j] + hw2[j + 64] * hb[j + 64];
        #pragma unroll
        for (int off = 32; off > 0; off >>= 1) p += __shfl_down(p, off);
        if (j == 0) {
            float z = p + hb2[0];
            scores_tmp[b * NW + w0 + win] = 5.0f / (1.0f + expf(-z));
        }
    }
}

// ---------------------------------------------------------------------------
__global__ void finalize_kernel(const float* __restrict__ tmp, float* __restrict__ out) {
    int w = blockIdx.x * 256 + threadIdx.x;
    if (w < NW) {
        float s = 0.0f;
        #pragma unroll
        for (int b = 0; b < BATCH; ++b) s += tmp[b * NW + w];
        s *= 0.125f;
        out[w] = s;
        out[NW + w] = (s < 3.5f) ? 1.0f : 0.0f;
    }
}

// ---------------------------------------------------------------------------
extern "C" void kernel_launch(void* const* d_in, const int* in_sizes, int n_in,
                              void* d_out, int out_size, void* d_ws, size_t ws_size,
                              hipStream_t stream) {
    const float* lat  = (const float*)d_in[0];
    const float* c0w  = (const float*)d_in[1];
    const float* c0b  = (const float*)d_in[2];
    const float* c1w  = (const float*)d_in[3];
    const float* c1b  = (const float*)d_in[4];
    const float* c2w  = (const float*)d_in[5];
    const float* c2b  = (const float*)d_in[6];
    const float* hw1  = (const float*)d_in[7];
    const float* hb1  = (const float*)d_in[8];
    const float* hw2  = (const float*)d_in[9];
    const float* hb2  = (const float*)d_in[10];

    // workspace layout
    bf16* p0   = (bf16*)d_ws;                                 // 458752 B
    bf16* p1   = (bf16*)((char*)d_ws + 458752);               // 163840 B
    bf16* p2   = (bf16*)((char*)d_ws + 622592);               // 163840 B
    bf16* hw1b = (bf16*)((char*)d_ws + 786432);               //  32768 B
    float* tmp = (float*)((char*)d_ws + 819200);              //  32000 B

    prep_kernel<<<1600, 256, 0, stream>>>(c0w, c1w, c2w, hw1, p0, p1, p2, hw1b);
    critic_kernel<<<BATCH * (NW / 4), 256, 0, stream>>>(lat, p0, c0b, p1, c1b, p2, c2b,
                                                        hw1b, hb1, hw2, hb2, tmp);
    finalize_kernel<<<4, 256, 0, stream>>>(tmp, (float*)d_out);
}